// Round 11
// baseline (290.292 us; speedup 1.0000x reference)
//
#include <hip/hip_runtime.h>
#include <stdint.h>

#define SEQ    4096
#define EMBED  1024
#define NHEAD  16
#define HDIM   64
#define WIN    256
#define BSZ    2
#define M_TOT  (BSZ * SEQ)   // 8192
#define N_QKV  3072
#define N_QK   2048
#define K_DIM  1024
#define LOG2E  1.4426950408889634f

typedef __attribute__((ext_vector_type(8))) __bf16 bf16x8;
typedef __attribute__((ext_vector_type(4))) float  f32x4;

__device__ __forceinline__ unsigned short f2bf(float f) {
  union { float f; unsigned int u; } c; c.f = f;
  unsigned int u = c.u;
  unsigned int r = (u + 0x7FFFu + ((u >> 16) & 1u)) >> 16;
  return (unsigned short)r;
}

// packed f32x2 -> bf16x2 (RNE, same as f2bf) in ONE VALU instr
__device__ __forceinline__ unsigned int cvt_pk_bf16(float lo, float hi) {
  unsigned int r;
  asm("v_cvt_pk_bf16_f32 %0, %1, %2" : "=v"(r) : "v"(lo), "v"(hi));
  return r;
}

__device__ __forceinline__ void gl2lds16(const void* g, void* l) {
  __builtin_amdgcn_global_load_lds((const __attribute__((address_space(1))) void*)g,
                                   (__attribute__((address_space(3))) void*)l, 16, 0, 0);
}

// ---- merged cast kernel: blocks [0,8192) convert hidden_states (fp32->bf16),
// blocks [8192, 8192+3072) transpose+cast the three weight matrices.
__global__ __launch_bounds__(256) void cvt_all(const float* __restrict__ in,
                                               unsigned short* __restrict__ out,
                                               const float* __restrict__ Wq,
                                               const float* __restrict__ Wk,
                                               const float* __restrict__ Wv,
                                               unsigned short* __restrict__ Wt) {
  __shared__ float t[32][33];
  int tid = threadIdx.x;
  if (blockIdx.x < 8192) {
    int i = (blockIdx.x * 256 + tid) * 4;
    float4 v = *(const float4*)(in + i);
    ushort4 o;
    o.x = f2bf(v.x); o.y = f2bf(v.y); o.z = f2bf(v.z); o.w = f2bf(v.w);
    *(ushort4*)(out + i) = o;
  } else {
    int wb = blockIdx.x - 8192;                  // 0..3071
    int z  = wb >> 10;                           // 0..2
    int rem = wb & 1023;
    int kb = (rem & 31) * 32, nb = (rem >> 5) * 32;
    const float* W = (z == 0) ? Wq : (z == 1) ? Wk : Wv;
    int tx = tid & 31, ty = tid >> 5;            // (32,8)
    for (int it = 0; it < 4; ++it) {
      int k = kb + ty + it * 8;
      t[ty + it * 8][tx] = W[(size_t)k * 1024 + nb + tx];
    }
    __syncthreads();
    for (int it = 0; it < 4; ++it) {
      int n = nb + ty + it * 8;
      Wt[(size_t)(z * 1024 + n) * 1024 + kb + tx] = f2bf(t[tx][ty + it * 8]);
    }
  }
}

// ---- fused QKV GEMM: 128(M)x384(N) tile, BK=64, 8 waves (2Mx4N -> 64x96/wave).
// Grid 64x8 = 512 blocks = exactly 2 rounds of 256 CUs. R7 (70.3-72.0 us, ~730 TF):
// 3 phases, 6 barriers/K-tile, MFMA clusters 16/16/16, counted vmcnt(6).
// Ledger (induction-verified):
//   p0: read af(8)+bf01(4); stage A(t+1)->alt; barrier; MFMA j01; barrier
//   p1: read bf23(4); barrier; MFMA j23; barrier
//   p2: read bf45(4); barrier [ALL A+B reads of tile t done];
//       stage B0,B1,B2(t+2)->cur; MFMA j45; vmcnt(6); barrier
// Gate: outstanding = B(t+1)6 + A(t+1)2 + B(t+2)6 = 14 -> vmcnt(6) retires
// A(t+1)+B(t+1). Drain vmcnt(0) at t>=14. T2 XOR-swizzle, XCD swizzle, T5.
// FROZEN as control.
__global__ __launch_bounds__(512, 2) void qkv_gemm(const unsigned short* __restrict__ A,   // h bf16 [8192][1024]
                                                   const unsigned short* __restrict__ Bt,  // Wt [3072][1024]
                                                   const float* __restrict__ bq,
                                                   const float* __restrict__ bk,
                                                   const float* __restrict__ bv,
                                                   unsigned short* __restrict__ C,         // qk [8192][2048]
                                                   unsigned short* __restrict__ Vt) {      // vtg [2048][4096]
  __shared__ unsigned short As[2][128 * 64];     // 2 x 16 KB
  __shared__ unsigned short Bs[2][384 * 64];     // 2 x 48 KB  (total 128 KB)
  int tid  = threadIdx.x;
  int lane = tid & 63, wave = tid >> 6;          // 8 waves
  int ln   = lane & 15, quad = lane >> 4;
  // bijective XCD swizzle: 512 blocks, 64 contiguous per XCD
  int flat = blockIdx.y * 8 + blockIdx.x;        // 0..511
  int swz  = (flat & 7) * 64 + (flat >> 3);
  int m0 = (swz >> 3) * 128, n0 = (swz & 7) * 384;
  int wy = wave >> 2, wx = wave & 3;             // per-wave 64M x 96N
  f32x4 acc[4][6];
#pragma unroll
  for (int i = 0; i < 4; ++i)
#pragma unroll
    for (int j = 0; j < 6; ++j) acc[i][j] = (f32x4){0.f, 0.f, 0.f, 0.f};

  int c8 = tid & 7;

  // region = 128 rows x 64 cols (16 KB) = 2 sweeps of 512 thr x 16 B
#define STG_A(buf, kt)                                                           \
  do {                                                                           \
    _Pragma("unroll")                                                            \
    for (int s = 0; s < 2; ++s) {                                                \
      int r = s * 64 + (tid >> 3); int cg = c8 ^ (r & 7);                        \
      gl2lds16(A + (size_t)(m0 + r) * K_DIM + (size_t)(kt) * 64 + cg * 8,        \
               &As[buf][r * 64 + c8 * 8]);                                       \
    }                                                                            \
  } while (0)
#define STG_B(buf, jreg, kt)                                                     \
  do {                                                                           \
    _Pragma("unroll")                                                            \
    for (int s = 0; s < 2; ++s) {                                                \
      int r = s * 64 + (tid >> 3); int gr = (jreg) * 128 + r;                    \
      int cg = c8 ^ (gr & 7);                                                    \
      gl2lds16(Bt + (size_t)(n0 + gr) * K_DIM + (size_t)(kt) * 64 + cg * 8,      \
               &Bs[buf][gr * 64 + c8 * 8]);                                      \
    }                                                                            \
  } while (0)

  // prologue: tile0 (A+B) + B(1); 14 outstanding -> vmcnt(6) retires tile 0
  STG_A(0, 0); STG_B(0, 0, 0); STG_B(0, 1, 0); STG_B(0, 2, 0);
  STG_B(1, 0, 1); STG_B(1, 1, 1); STG_B(1, 2, 1);
  asm volatile("s_waitcnt vmcnt(6)" ::: "memory");
  __builtin_amdgcn_s_barrier();

  int aBase = wy * 64, bBase = wx * 96;

#pragma unroll 1
  for (int t = 0; t < 16; ++t) {
    int cur = t & 1;
    const unsigned short* as = As[cur];
    const unsigned short* bs = Bs[cur];
    bf16x8 af[4][2], bf01[2][2], bf23[2][2], bf45[2][2];

    // ---- p0: read af(8) + bf01(4); stage A(t+1)->alt; MFMA j0,j1
#pragma unroll
    for (int i2 = 0; i2 < 4; ++i2) {
      int row = aBase + i2 * 16 + ln;
#pragma unroll
      for (int ks = 0; ks < 2; ++ks) {
        int c = (ks * 4 + quad) ^ (row & 7);
        af[i2][ks] = *(const bf16x8*)&as[row * 64 + c * 8];
      }
    }
#pragma unroll
    for (int j2 = 0; j2 < 2; ++j2) {
      int row = bBase + j2 * 16 + ln;
#pragma unroll
      for (int ks = 0; ks < 2; ++ks) {
        int c = (ks * 4 + quad) ^ (row & 7);
        bf01[j2][ks] = *(const bf16x8*)&bs[row * 64 + c * 8];
      }
    }
    if (t < 15) STG_A(cur ^ 1, t + 1);
    __builtin_amdgcn_s_barrier();
    __builtin_amdgcn_s_setprio(1);
#pragma unroll
    for (int ks = 0; ks < 2; ++ks)
#pragma unroll
      for (int i2 = 0; i2 < 4; ++i2)
#pragma unroll
        for (int j2 = 0; j2 < 2; ++j2)
          acc[i2][j2] = __builtin_amdgcn_mfma_f32_16x16x32_bf16(af[i2][ks], bf01[j2][ks], acc[i2][j2], 0, 0, 0);
    __builtin_amdgcn_s_setprio(0);
    __builtin_amdgcn_s_barrier();

    // ---- p1: read bf23(4); MFMA j2,j3
#pragma unroll
    for (int j2 = 0; j2 < 2; ++j2) {
      int row = bBase + 32 + j2 * 16 + ln;
#pragma unroll
      for (int ks = 0; ks < 2; ++ks) {
        int c = (ks * 4 + quad) ^ (row & 7);
        bf23[j2][ks] = *(const bf16x8*)&bs[row * 64 + c * 8];
      }
    }
    __builtin_amdgcn_s_barrier();
    __builtin_amdgcn_s_setprio(1);
#pragma unroll
    for (int ks = 0; ks < 2; ++ks)
#pragma unroll
      for (int i2 = 0; i2 < 4; ++i2)
#pragma unroll
        for (int j2 = 0; j2 < 2; ++j2)
          acc[i2][2 + j2] = __builtin_amdgcn_mfma_f32_16x16x32_bf16(af[i2][ks], bf23[j2][ks], acc[i2][2 + j2], 0, 0, 0);
    __builtin_amdgcn_s_setprio(0);
    __builtin_amdgcn_s_barrier();

    // ---- p2: read bf45(4); barrier (ALL A+B reads of tile t complete);
    //          stage B0,B1,B2(t+2)->cur; MFMA j4,j5; gate
#pragma unroll
    for (int j2 = 0; j2 < 2; ++j2) {
      int row = bBase + 64 + j2 * 16 + ln;
#pragma unroll
      for (int ks = 0; ks < 2; ++ks) {
        int c = (ks * 4 + quad) ^ (row & 7);
        bf45[j2][ks] = *(const bf16x8*)&bs[row * 64 + c * 8];
      }
    }
    __builtin_amdgcn_s_barrier();
    if (t < 14) { STG_B(cur, 0, t + 2); STG_B(cur, 1, t + 2); STG_B(cur, 2, t + 2); }
    __builtin_amdgcn_s_setprio(1);
#pragma unroll
    for (int ks = 0; ks < 2; ++ks)
#pragma unroll
      for (int i2 = 0; i2 < 4; ++i2)
#pragma unroll
        for (int j2 = 0; j2 < 2; ++j2)
          acc[i2][4 + j2] = __builtin_amdgcn_mfma_f32_16x16x32_bf16(af[i2][ks], bf45[j2][ks], acc[i2][4 + j2], 0, 0, 0);
    __builtin_amdgcn_s_setprio(0);
    if (t < 14) asm volatile("s_waitcnt vmcnt(6)" ::: "memory");
    else        asm volatile("s_waitcnt vmcnt(0)" ::: "memory");
    __builtin_amdgcn_s_barrier();
  }
#undef STG_A
#undef STG_B

  // epilogue: n may cross the Q/K vs V boundary mid-tile -> branch per j
#pragma unroll
  for (int j = 0; j < 6; ++j) {
    int n = n0 + wx * 96 + j * 16 + ln;
    if (n < N_QK) {
      float bias, scl;
      if (n < 1024) { bias = bq[n];        scl = 0.125f * LOG2E; }  // fold 1/sqrt(64) and log2(e)
      else          { bias = bk[n - 1024]; scl = 1.f; }
#pragma unroll
      for (int i = 0; i < 4; ++i) {
        int mb = m0 + wy * 64 + i * 16 + quad * 4;
#pragma unroll
        for (int r = 0; r < 4; ++r) {
          float v = (acc[i][j][r] + bias) * scl;
          C[(size_t)(mb + r) * N_QK + n] = f2bf(v);
        }
      }
    } else {
      int hd = n - 2048;                     // head*64 + d
      float bias = bv[hd];
#pragma unroll
      for (int i = 0; i < 4; ++i) {
        int mb  = m0 + wy * 64 + i * 16 + quad * 4;
        int bb  = mb >> 12;                  // / SEQ
        int pos = mb & (SEQ - 1);
        ushort4 pk;
        pk.x = f2bf(acc[i][j][0] + bias);
        pk.y = f2bf(acc[i][j][1] + bias);
        pk.z = f2bf(acc[i][j][2] + bias);
        pk.w = f2bf(acc[i][j][3] + bias);
        *(ushort4*)&Vt[((size_t)bb * (NHEAD * HDIM) + hd) * SEQ + pos] = pk;
      }
    }
  }
}

// ------- banded flash attention, LDS-FREE -------
// R11: kf/vf fragments read DIRECTLY from global (qk/vtg are L3-resident, 48MB;
// K rows contiguous in qk, V^T rows contiguous in vtg -> every fragment is a
// clean 16B global_load_dwordx4). Rationale: R8/R9/R10 falsified staging-,
// LDS-BW- and barrier-count theories (4 structural variants within +-5us);
// every pipe <30% busy -> the LDS round-trip itself (stage+2 barriers+ds_read
// serialization, 20 barrier-drains/block) is the structural cost. Guide
// common-mistake #7 (measured, attn S=1024): dropping LDS staging when data
// L2-fits was +26%. L2/L3 provides the 8-way intra-block reuse dedup instead.
// ZERO barriers, fully independent waves; vf loads issued BEFORE the softmax
// VALU chain (latency hides under it); occupancy VGPR-limited (~4-5 waves/SIMD).
// Math/shuffle/pack identical to proven R1 wave code (64 q/block, 4 waves).
__global__ __launch_bounds__(256) void attn(const unsigned short* __restrict__ qk,
                                            const unsigned short* __restrict__ vtg,
                                            float* __restrict__ out) {
  int tid  = threadIdx.x;
  int lane = tid & 63, wave = tid >> 6;          // wave 0..3, 16 queries each
  int ln   = lane & 15, quad = lane >> 4;
  int bx = blockIdx.x;
  int lx = ((bx & 7) << 3) | (bx >> 3);          // bijective XCD swizzle (64 = 8x8)
  int q0 = lx * 64, head = blockIdx.y, b = blockIdx.z;
  size_t baseRow = (size_t)b * SEQ;
  // K fragment base: row (baseRow + k), dims quad*8 (+32 for kf1)
  const unsigned short* kfp = qk + 1024 + head * HDIM + quad * 8;
  // V^T fragment base: d-row (dt*16+ln), seq-col (kt + ks*32 + quad*8)
  const unsigned short* vrow = vtg + ((size_t)(b * NHEAD + head) * HDIM) * SEQ + quad * 8;

  // Q fragments from global (B-operand: n=q=ln, k = ks*32 + quad*8 + j)
  bf16x8 qf[2];
  {
    size_t ro = (baseRow + q0 + wave * 16 + ln) * (size_t)N_QK + head * HDIM + quad * 8;
    qf[0] = *(const bf16x8*)&qk[ro];
    qf[1] = *(const bf16x8*)&qk[ro + 32];
  }

  float l_st = 0.f;
  f32x4 o_acc[4];                                // O^T: row d = dt*16+quad*4+r, col q = ln
  for (int dt = 0; dt < 4; ++dt) o_acc[dt] = (f32x4){0.f, 0.f, 0.f, 0.f};

  int lo = (q0 >= 256) ? 0 : (256 - q0) / 64;
  int hi = (SEQ + 256 - q0) / 64; if (hi > 9) hi = 9;

  int srcA = ((lane & 16) << 1) | ln;            // (quad&1)*32 + ln
  int srcB = srcA + 16;
  bool hiQ = (lane & 32) != 0;                   // quad >= 2

  for (int t = lo; t < hi; ++t) {
    int kt = q0 - 256 + t * 64;

    // K fragments for this tile: 8 x 16B direct global loads (L2/L3 hits)
    bf16x8 kf0[4], kf1[4];
#pragma unroll
    for (int nt = 0; nt < 4; ++nt) {
      size_t kr = (baseRow + (size_t)(kt + nt * 16 + ln)) * (size_t)N_QK;
      kf0[nt] = *(const bf16x8*)&kfp[kr];
      kf1[nt] = *(const bf16x8*)&kfp[kr + 32];
    }
    // V fragments issued EARLY: latency hides under QK^T MFMAs + softmax VALU
    bf16x8 vf[2][4];
#pragma unroll
    for (int ks = 0; ks < 2; ++ks)
#pragma unroll
      for (int dt = 0; dt < 4; ++dt)
        vf[ks][dt] = *(const bf16x8*)&vrow[(size_t)(dt * 16 + ln) * SEQ + kt + ks * 32];

    // S^T = K Q^T : row k = kt + nt*16 + quad*4 + r, col q = ln
    f32x4 s[4];
    __builtin_amdgcn_s_setprio(1);
#pragma unroll
    for (int nt = 0; nt < 4; ++nt) {
      f32x4 z = (f32x4){0.f, 0.f, 0.f, 0.f};
      z = __builtin_amdgcn_mfma_f32_16x16x32_bf16(kf0[nt], qf[0], z, 0, 0, 0);
      z = __builtin_amdgcn_mfma_f32_16x16x32_bf16(kf1[nt], qf[1], z, 0, 0, 0);
      s[nt] = z;
    }
    __builtin_amdgcn_s_setprio(0);

    if (t == 0 || t == 8) {                            // only edge offsets need band mask
      int qq = q0 + wave * 16 + ln;
#pragma unroll
      for (int nt = 0; nt < 4; ++nt) {
        int kb = kt + nt * 16 + quad * 4 - qq;
#pragma unroll
        for (int r = 0; r < 4; ++r) {
          int dd = kb + r;
          if (dd < -WIN || dd > WIN) s[nt][r] = -INFINITY;
        }
      }
    }

    // fixed-max softmax (scores in log2 units; masked -> exp2(-inf) = 0)
    float rs = 0.f;
#pragma unroll
    for (int nt = 0; nt < 4; ++nt)
#pragma unroll
      for (int r = 0; r < 4; ++r) {
        float p = exp2f(s[nt][r]);
        s[nt][r] = p;
        rs += p;
      }
    l_st += rs;

    // pack P to bf16 pairs (per nt: elements 0,1 and 2,3) — one v_cvt_pk each
    unsigned int p01[4], p23[4];
#pragma unroll
    for (int nt = 0; nt < 4; ++nt) {
      p01[nt] = cvt_pk_bf16(s[nt][0], s[nt][1]);
      p23[nt] = cvt_pk_bf16(s[nt][2], s[nt][3]);
    }

    // O^T += V^T P : A = V^T [d][k] (vf regs), B = P[k][q] built via shuffles
#pragma unroll
    for (int ks = 0; ks < 2; ++ks) {
      int ntA = 2 * ks, ntB = 2 * ks + 1;
      unsigned int a0 = (unsigned int)__shfl((int)p01[ntA], srcA);
      unsigned int a1 = (unsigned int)__shfl((int)p23[ntA], srcA);
      unsigned int a2 = (unsigned int)__shfl((int)p01[ntA], srcB);
      unsigned int a3 = (unsigned int)__shfl((int)p23[ntA], srcB);
      unsigned int b0 = (unsigned int)__shfl((int)p01[ntB], srcA);
      unsigned int b1 = (unsigned int)__shfl((int)p23[ntB], srcA);
      unsigned int b2 = (unsigned int)__shfl((int)p01[ntB], srcB);
      unsigned int b3 = (unsigned int)__shfl((int)p23[ntB], srcB);
      union { uint4 u; bf16x8 v; } pf;
      pf.u.x = hiQ ? b0 : a0;
      pf.u.y = hiQ ? b1 : a1;
      pf.u.z = hiQ ? b2 : a2;
      pf.u.w = hiQ ? b3 : a3;
      __builtin_amdgcn_s_setprio(1);
#pragma unroll
      for (int dt = 0; dt < 4; ++dt)
        o_acc[dt] = __builtin_amdgcn_mfma_f32_16x16x32_bf16(vf[ks][dt], pf.v, o_acc[dt], 0, 0, 0);
      __builtin_amdgcn_s_setprio(0);
    }
  }

  // l reduction across the 4 quads of column q=ln; per-lane inverse, float4 stores
  float l = l_st;
  l += __shfl_xor(l, 16);
  l += __shfl_xor(l, 32);
  float inv = 1.0f / l;
  int qpos = q0 + wave * 16 + ln;
  float* ob = out + (baseRow + qpos) * (size_t)EMBED + head * HDIM + quad * 4;
  for (int dt = 0; dt < 4; ++dt) {
    float4 v;
    v.x = o_acc[dt][0] * inv;
    v.y = o_acc[dt][1] * inv;
    v.z = o_acc[dt][2] * inv;
    v.w = o_acc[dt][3] * inv;
    *(float4*)(ob + dt * 16) = v;
  }
}

extern "C" void kernel_launch(void* const* d_in, const int* in_sizes, int n_in,
                              void* d_out, int out_size, void* d_ws, size_t ws_size,
                              hipStream_t stream) {
  const float* h  = (const float*)d_in[0];
  const float* Wq = (const float*)d_in[1];
  const float* bq = (const float*)d_in[2];
  const float* Wk = (const float*)d_in[3];
  const float* bk = (const float*)d_in[4];
  const float* Wv = (const float*)d_in[5];
  const float* bv = (const float*)d_in[6];
  float* out = (float*)d_out;

  unsigned short* h_bf  = (unsigned short*)d_ws;                 // 16 MB
  unsigned short* wt_bf = h_bf + (size_t)M_TOT * K_DIM;          //  6 MB
  unsigned short* qk    = wt_bf + (size_t)N_QKV * K_DIM;         // 32 MB
  unsigned short* vtg   = qk + (size_t)M_TOT * N_QK;             // 16 MB  (total 70 MB)

  cvt_all<<<8192 + 3072, 256, 0, stream>>>(h, h_bf, Wq, Wk, Wv, wt_bf);
  qkv_gemm<<<dim3(8, 64), 512, 0, stream>>>(h_bf, wt_bf, bq, bk, bv, qk, vtg);
  attn<<<dim3(SEQ / 64, NHEAD, BSZ), 256, 0, stream>>>(qk, vtg, out);
}

// Round 13
// 205.146 us; speedup vs baseline: 1.4151x; 1.4151x over previous
//
#include <hip/hip_runtime.h>
#include <stdint.h>

#define SEQ    4096
#define EMBED  1024
#define NHEAD  16
#define HDIM   64
#define WIN    256
#define BSZ    2
#define M_TOT  (BSZ * SEQ)   // 8192
#define N_QKV  3072
#define N_QK   2048
#define K_DIM  1024
#define LOG2E  1.4426950408889634f

typedef __attribute__((ext_vector_type(8))) __bf16 bf16x8;
typedef __attribute__((ext_vector_type(4))) float  f32x4;

__device__ __forceinline__ unsigned short f2bf(float f) {
  union { float f; unsigned int u; } c; c.f = f;
  unsigned int u = c.u;
  unsigned int r = (u + 0x7FFFu + ((u >> 16) & 1u)) >> 16;
  return (unsigned short)r;
}

// packed f32x2 -> bf16x2 (RNE, same as f2bf) in ONE VALU instr
__device__ __forceinline__ unsigned int cvt_pk_bf16(float lo, float hi) {
  unsigned int r;
  asm("v_cvt_pk_bf16_f32 %0, %1, %2" : "=v"(r) : "v"(lo), "v"(hi));
  return r;
}

__device__ __forceinline__ void gl2lds16(const void* g, void* l) {
  __builtin_amdgcn_global_load_lds((const __attribute__((address_space(1))) void*)g,
                                   (__attribute__((address_space(3))) void*)l, 16, 0, 0);
}

// ---- merged cast kernel: blocks [0,8192) convert hidden_states (fp32->bf16),
// blocks [8192, 8192+3072) transpose+cast the three weight matrices.
__global__ __launch_bounds__(256) void cvt_all(const float* __restrict__ in,
                                               unsigned short* __restrict__ out,
                                               const float* __restrict__ Wq,
                                               const float* __restrict__ Wk,
                                               const float* __restrict__ Wv,
                                               unsigned short* __restrict__ Wt) {
  __shared__ float t[32][33];
  int tid = threadIdx.x;
  if (blockIdx.x < 8192) {
    int i = (blockIdx.x * 256 + tid) * 4;
    float4 v = *(const float4*)(in + i);
    ushort4 o;
    o.x = f2bf(v.x); o.y = f2bf(v.y); o.z = f2bf(v.z); o.w = f2bf(v.w);
    *(ushort4*)(out + i) = o;
  } else {
    int wb = blockIdx.x - 8192;                  // 0..3071
    int z  = wb >> 10;                           // 0..2
    int rem = wb & 1023;
    int kb = (rem & 31) * 32, nb = (rem >> 5) * 32;
    const float* W = (z == 0) ? Wq : (z == 1) ? Wk : Wv;
    int tx = tid & 31, ty = tid >> 5;            // (32,8)
    for (int it = 0; it < 4; ++it) {
      int k = kb + ty + it * 8;
      t[ty + it * 8][tx] = W[(size_t)k * 1024 + nb + tx];
    }
    __syncthreads();
    for (int it = 0; it < 4; ++it) {
      int n = nb + ty + it * 8;
      Wt[(size_t)(z * 1024 + n) * 1024 + kb + tx] = f2bf(t[tx][ty + it * 8]);
    }
  }
}

// ---- fused QKV GEMM: 128(M)x384(N) tile, BK=64, 8 waves (2Mx4N -> 64x96/wave).
// Grid 64x8 = 512 blocks = exactly 2 rounds of 256 CUs. R7 schedule (70.3 us):
// 3 phases, 6 barriers/K-tile, MFMA clusters 16/16/16, counted vmcnt(6).
// R12 (resubmit after infra failure): XCD swizzle re-mapped for L2 residency.
// Old: each XCD cycled ALL 8 B-panels (6MB > 4MB L2) -> B thrash (FETCH 57.5MB
// vs 22MB ideal), staged-B loads at L3 latency. New (bijective):
// m_idx = xcd*8 + (kk&7), n_idx = kk>>3 — the ~32 co-resident blocks per XCD
// span 4 B-panels (3MB, L2-fits) x 8 A-panels (2MB).
// Ledger (induction-verified, unchanged):
//   p0: read af(8)+bf01(4); stage A(t+1)->alt; barrier; MFMA j01; barrier
//   p1: read bf23(4); barrier; MFMA j23; barrier
//   p2: read bf45(4); barrier [ALL A+B reads of tile t done];
//       stage B0,B1,B2(t+2)->cur; MFMA j45; vmcnt(6); barrier
// Gate: outstanding = B(t+1)6 + A(t+1)2 + B(t+2)6 = 14 -> vmcnt(6) retires
// A(t+1)+B(t+1). Drain vmcnt(0) at t>=14. T2 XOR-swizzle, T5 setprio.
__global__ __launch_bounds__(512, 2) void qkv_gemm(const unsigned short* __restrict__ A,   // h bf16 [8192][1024]
                                                   const unsigned short* __restrict__ Bt,  // Wt [3072][1024]
                                                   const float* __restrict__ bq,
                                                   const float* __restrict__ bk,
                                                   const float* __restrict__ bv,
                                                   unsigned short* __restrict__ C,         // qk [8192][2048]
                                                   unsigned short* __restrict__ Vt) {      // vtg [2048][4096]
  __shared__ unsigned short As[2][128 * 64];     // 2 x 16 KB
  __shared__ unsigned short Bs[2][384 * 64];     // 2 x 48 KB  (total 128 KB)
  int tid  = threadIdx.x;
  int lane = tid & 63, wave = tid >> 6;          // 8 waves
  int ln   = lane & 15, quad = lane >> 4;
  // L2-resident XCD swizzle (bijective): 512 blocks, 64 per XCD.
  int flat = blockIdx.y * 8 + blockIdx.x;        // 0..511
  int xcd  = flat & 7, kk = flat >> 3;           // kk 0..63 per XCD
  int m0 = (xcd * 8 + (kk & 7)) * 128;           // 8 A-panels per XCD (2MB)
  int n0 = (kk >> 3) * 384;                      // 4 B-panels per 32-block window (3MB)
  int wy = wave >> 2, wx = wave & 3;             // per-wave 64M x 96N
  f32x4 acc[4][6];
#pragma unroll
  for (int i = 0; i < 4; ++i)
#pragma unroll
    for (int j = 0; j < 6; ++j) acc[i][j] = (f32x4){0.f, 0.f, 0.f, 0.f};

  int c8 = tid & 7;

  // region = 128 rows x 64 cols (16 KB) = 2 sweeps of 512 thr x 16 B
#define STG_A(buf, kt)                                                           \
  do {                                                                           \
    _Pragma("unroll")                                                            \
    for (int s = 0; s < 2; ++s) {                                                \
      int r = s * 64 + (tid >> 3); int cg = c8 ^ (r & 7);                        \
      gl2lds16(A + (size_t)(m0 + r) * K_DIM + (size_t)(kt) * 64 + cg * 8,        \
               &As[buf][r * 64 + c8 * 8]);                                       \
    }                                                                            \
  } while (0)
#define STG_B(buf, jreg, kt)                                                     \
  do {                                                                           \
    _Pragma("unroll")                                                            \
    for (int s = 0; s < 2; ++s) {                                                \
      int r = s * 64 + (tid >> 3); int gr = (jreg) * 128 + r;                    \
      int cg = c8 ^ (gr & 7);                                                    \
      gl2lds16(Bt + (size_t)(n0 + gr) * K_DIM + (size_t)(kt) * 64 + cg * 8,      \
               &Bs[buf][gr * 64 + c8 * 8]);                                      \
    }                                                                            \
  } while (0)

  // prologue: tile0 (A+B) + B(1); 14 outstanding -> vmcnt(6) retires tile 0
  STG_A(0, 0); STG_B(0, 0, 0); STG_B(0, 1, 0); STG_B(0, 2, 0);
  STG_B(1, 0, 1); STG_B(1, 1, 1); STG_B(1, 2, 1);
  asm volatile("s_waitcnt vmcnt(6)" ::: "memory");
  __builtin_amdgcn_s_barrier();

  int aBase = wy * 64, bBase = wx * 96;

#pragma unroll 1
  for (int t = 0; t < 16; ++t) {
    int cur = t & 1;
    const unsigned short* as = As[cur];
    const unsigned short* bs = Bs[cur];
    bf16x8 af[4][2], bf01[2][2], bf23[2][2], bf45[2][2];

    // ---- p0: read af(8) + bf01(4); stage A(t+1)->alt; MFMA j0,j1
#pragma unroll
    for (int i2 = 0; i2 < 4; ++i2) {
      int row = aBase + i2 * 16 + ln;
#pragma unroll
      for (int ks = 0; ks < 2; ++ks) {
        int c = (ks * 4 + quad) ^ (row & 7);
        af[i2][ks] = *(const bf16x8*)&as[row * 64 + c * 8];
      }
    }
#pragma unroll
    for (int j2 = 0; j2 < 2; ++j2) {
      int row = bBase + j2 * 16 + ln;
#pragma unroll
      for (int ks = 0; ks < 2; ++ks) {
        int c = (ks * 4 + quad) ^ (row & 7);
        bf01[j2][ks] = *(const bf16x8*)&bs[row * 64 + c * 8];
      }
    }
    if (t < 15) STG_A(cur ^ 1, t + 1);
    __builtin_amdgcn_s_barrier();
    __builtin_amdgcn_s_setprio(1);
#pragma unroll
    for (int ks = 0; ks < 2; ++ks)
#pragma unroll
      for (int i2 = 0; i2 < 4; ++i2)
#pragma unroll
        for (int j2 = 0; j2 < 2; ++j2)
          acc[i2][j2] = __builtin_amdgcn_mfma_f32_16x16x32_bf16(af[i2][ks], bf01[j2][ks], acc[i2][j2], 0, 0, 0);
    __builtin_amdgcn_s_setprio(0);
    __builtin_amdgcn_s_barrier();

    // ---- p1: read bf23(4); MFMA j2,j3
#pragma unroll
    for (int j2 = 0; j2 < 2; ++j2) {
      int row = bBase + 32 + j2 * 16 + ln;
#pragma unroll
      for (int ks = 0; ks < 2; ++ks) {
        int c = (ks * 4 + quad) ^ (row & 7);
        bf23[j2][ks] = *(const bf16x8*)&bs[row * 64 + c * 8];
      }
    }
    __builtin_amdgcn_s_barrier();
    __builtin_amdgcn_s_setprio(1);
#pragma unroll
    for (int ks = 0; ks < 2; ++ks)
#pragma unroll
      for (int i2 = 0; i2 < 4; ++i2)
#pragma unroll
        for (int j2 = 0; j2 < 2; ++j2)
          acc[i2][2 + j2] = __builtin_amdgcn_mfma_f32_16x16x32_bf16(af[i2][ks], bf23[j2][ks], acc[i2][2 + j2], 0, 0, 0);
    __builtin_amdgcn_s_setprio(0);
    __builtin_amdgcn_s_barrier();

    // ---- p2: read bf45(4); barrier (ALL A+B reads of tile t complete);
    //          stage B0,B1,B2(t+2)->cur; MFMA j4,j5; gate
#pragma unroll
    for (int j2 = 0; j2 < 2; ++j2) {
      int row = bBase + 64 + j2 * 16 + ln;
#pragma unroll
      for (int ks = 0; ks < 2; ++ks) {
        int c = (ks * 4 + quad) ^ (row & 7);
        bf45[j2][ks] = *(const bf16x8*)&bs[row * 64 + c * 8];
      }
    }
    __builtin_amdgcn_s_barrier();
    if (t < 14) { STG_B(cur, 0, t + 2); STG_B(cur, 1, t + 2); STG_B(cur, 2, t + 2); }
    __builtin_amdgcn_s_setprio(1);
#pragma unroll
    for (int ks = 0; ks < 2; ++ks)
#pragma unroll
      for (int i2 = 0; i2 < 4; ++i2)
#pragma unroll
        for (int j2 = 0; j2 < 2; ++j2)
          acc[i2][4 + j2] = __builtin_amdgcn_mfma_f32_16x16x32_bf16(af[i2][ks], bf45[j2][ks], acc[i2][4 + j2], 0, 0, 0);
    __builtin_amdgcn_s_setprio(0);
    if (t < 14) asm volatile("s_waitcnt vmcnt(6)" ::: "memory");
    else        asm volatile("s_waitcnt vmcnt(0)" ::: "memory");
    __builtin_amdgcn_s_barrier();
  }
#undef STG_A
#undef STG_B

  // epilogue: n may cross the Q/K vs V boundary mid-tile -> branch per j
#pragma unroll
  for (int j = 0; j < 6; ++j) {
    int n = n0 + wx * 96 + j * 16 + ln;
    if (n < N_QK) {
      float bias, scl;
      if (n < 1024) { bias = bq[n];        scl = 0.125f * LOG2E; }  // fold 1/sqrt(64) and log2(e)
      else          { bias = bk[n - 1024]; scl = 1.f; }
#pragma unroll
      for (int i = 0; i < 4; ++i) {
        int mb = m0 + wy * 64 + i * 16 + quad * 4;
#pragma unroll
        for (int r = 0; r < 4; ++r) {
          float v = (acc[i][j][r] + bias) * scl;
          C[(size_t)(mb + r) * N_QK + n] = f2bf(v);
        }
      }
    } else {
      int hd = n - 2048;                     // head*64 + d
      float bias = bv[hd];
#pragma unroll
      for (int i = 0; i < 4; ++i) {
        int mb  = m0 + wy * 64 + i * 16 + quad * 4;
        int bb  = mb >> 12;                  // / SEQ
        int pos = mb & (SEQ - 1);
        ushort4 pk;
        pk.x = f2bf(acc[i][j][0] + bias);
        pk.y = f2bf(acc[i][j][1] + bias);
        pk.z = f2bf(acc[i][j][2] + bias);
        pk.w = f2bf(acc[i][j][3] + bias);
        *(ushort4*)&Vt[((size_t)bb * (NHEAD * HDIM) + hd) * SEQ + pos] = pk;
      }
    }
  }
}

// ------- banded flash attention -------
// R8 version EXACT (best total 206.9us): 128 q / block (8 waves x 16 q, 512
// thr), K/V staged via reg prefetch + LDS, 2 barriers/tile. R9 (dual-q),
// R10 (dbuf 1-barrier), R11 (LDS-free: 141us, MfmaUtil 5%, 16-row gathers
// exposed L2 latency) all regressed — R8 structure is the local optimum.
// Band mask: t<2 || t>=8 (interior in-band: dd in [64t-383,64t-193] subset
// of [-256,256] iff 2<=t<=7). 18.4 KB LDS.
__global__ __launch_bounds__(512) void attn(const unsigned short* __restrict__ qk,
                                            const unsigned short* __restrict__ vtg,
                                            float* __restrict__ out) {
  __shared__ unsigned short Kl[64 * 72];
  __shared__ unsigned short Vl[64 * 72];
  int tid  = threadIdx.x;
  int lane = tid & 63, wave = tid >> 6;          // wave 0..7, 16 queries each
  int ln   = lane & 15, quad = lane >> 4;
  int bx = blockIdx.x;                           // 0..31
  int lx = ((bx & 7) << 2) | (bx >> 3);          // bijective XCD swizzle (32 = 8x4)
  int q0 = lx * 128, head = blockIdx.y, b = blockIdx.z;
  size_t baseRow = (size_t)b * SEQ;
  const unsigned short* kptr = qk + 1024;
  const unsigned short* vrow = vtg + ((size_t)(b * NHEAD + head) * HDIM) * SEQ;

  // per-thread staging coordinates (constant across tiles)
  int sy = tid >> 3, sc = tid & 7;               // row 0..63, 16B chunk 0..7
  const unsigned short* kbase = kptr + (baseRow + sy) * (size_t)N_QK + head * HDIM + sc * 8;
  const unsigned short* vbase = vrow + (size_t)sy * SEQ + sc * 8;

  // Q fragments from global (B-operand: n=q=ln, k = ks*32 + quad*8 + j)
  bf16x8 qf[2];
  {
    size_t ro = (baseRow + q0 + wave * 16 + ln) * (size_t)N_QK + head * HDIM + quad * 8;
    qf[0] = *(const bf16x8*)&qk[ro];
    qf[1] = *(const bf16x8*)&qk[ro + 32];
  }

  float l_st = 0.f;
  f32x4 o_acc[4];                                // O^T: row d = dt*16+quad*4+r, col q = ln
  for (int dt = 0; dt < 4; ++dt) o_acc[dt] = (f32x4){0.f, 0.f, 0.f, 0.f};

  int lo = (q0 >= 256) ? 0 : (256 - q0) / 64;
  int hi = (SEQ + 256 - q0) / 64; if (hi > 10) hi = 10;

  uint4 pk, pv;
#define PREFETCH(KT)                                                        \
  {                                                                         \
    pk = *(const uint4*)&kbase[(size_t)(KT) * N_QK];                        \
    pv = *(const uint4*)&vbase[(KT)];                                       \
  }

  PREFETCH(q0 - 256 + lo * 64);

  int srcA = ((lane & 16) << 1) | ln;            // (quad&1)*32 + ln
  int srcB = srcA + 16;
  bool hiQ = (lane & 32) != 0;                   // quad >= 2

  for (int t = lo; t < hi; ++t) {
    int kt = q0 - 256 + t * 64;
    __syncthreads();                                   // A: prev-tile LDS reads drained
    *(uint4*)&Kl[sy * 72 + sc * 8] = pk;
    *(uint4*)&Vl[sy * 72 + sc * 8] = pv;
    __syncthreads();                                   // B: staging visible

    if (t + 1 < hi) { PREFETCH(kt + 64); }             // hide HBM latency behind compute

    // S^T = K Q^T : row k = kt + nt*16 + quad*4 + r, col q = ln  (kf loaded JIT)
    f32x4 s[4];
    __builtin_amdgcn_s_setprio(1);
    for (int nt = 0; nt < 4; ++nt) {
      bf16x8 kf0 = *(const bf16x8*)&Kl[(nt * 16 + ln) * 72 + quad * 8];
      bf16x8 kf1 = *(const bf16x8*)&Kl[(nt * 16 + ln) * 72 + 32 + quad * 8];
      f32x4 z = (f32x4){0.f, 0.f, 0.f, 0.f};
      z = __builtin_amdgcn_mfma_f32_16x16x32_bf16(kf0, qf[0], z, 0, 0, 0);
      z = __builtin_amdgcn_mfma_f32_16x16x32_bf16(kf1, qf[1], z, 0, 0, 0);
      s[nt] = z;
    }
    __builtin_amdgcn_s_setprio(0);

    if (t < 2 || t >= 8) {                             // only edge tiles need band mask
      int qq = q0 + wave * 16 + ln;
      for (int nt = 0; nt < 4; ++nt) {
        int kb = kt + nt * 16 + quad * 4 - qq;
        for (int r = 0; r < 4; ++r) {
          int dd = kb + r;
          if (dd < -WIN || dd > WIN) s[nt][r] = -INFINITY;
        }
      }
    }

    // fixed-max softmax (scores in log2 units; masked -> exp2(-inf) = 0)
    float rs = 0.f;
    for (int nt = 0; nt < 4; ++nt)
      for (int r = 0; r < 4; ++r) {
        float p = exp2f(s[nt][r]);
        s[nt][r] = p;
        rs += p;
      }
    l_st += rs;

    // pack P to bf16 pairs (per nt: elements 0,1 and 2,3) — one v_cvt_pk each
    unsigned int p01[4], p23[4];
    for (int nt = 0; nt < 4; ++nt) {
      p01[nt] = cvt_pk_bf16(s[nt][0], s[nt][1]);
      p23[nt] = cvt_pk_bf16(s[nt][2], s[nt][3]);
    }

    // O^T += V^T P : A = V^T [d][k] from Vl, B = P[k][q] built via shuffles
    for (int ks = 0; ks < 2; ++ks) {
      int ntA = 2 * ks, ntB = 2 * ks + 1;
      unsigned int a0 = (unsigned int)__shfl((int)p01[ntA], srcA);
      unsigned int a1 = (unsigned int)__shfl((int)p23[ntA], srcA);
      unsigned int a2 = (unsigned int)__shfl((int)p01[ntA], srcB);
      unsigned int a3 = (unsigned int)__shfl((int)p23[ntA], srcB);
      unsigned int b0 = (unsigned int)__shfl((int)p01[ntB], srcA);
      unsigned int b1 = (unsigned int)__shfl((int)p23[ntB], srcA);
      unsigned int b2 = (unsigned int)__shfl((int)p01[ntB], srcB);
      unsigned int b3 = (unsigned int)__shfl((int)p23[ntB], srcB);
      union { uint4 u; bf16x8 v; } pf;
      pf.u.x = hiQ ? b0 : a0;
      pf.u.y = hiQ ? b1 : a1;
      pf.u.z = hiQ ? b2 : a2;
      pf.u.w = hiQ ? b3 : a3;
      __builtin_amdgcn_s_setprio(1);
      for (int dt = 0; dt < 4; ++dt) {
        bf16x8 vf = *(const bf16x8*)&Vl[(dt * 16 + ln) * 72 + ks * 32 + quad * 8];
        o_acc[dt] = __builtin_amdgcn_mfma_f32_16x16x32_bf16(vf, pf.v, o_acc[dt], 0, 0, 0);
      }
      __builtin_amdgcn_s_setprio(0);
    }
  }

  // l reduction across the 4 quads of column q=ln; per-lane inverse, float4 stores
  float l = l_st;
  l += __shfl_xor(l, 16);
  l += __shfl_xor(l, 32);
  float inv = 1.0f / l;
  int qpos = q0 + wave * 16 + ln;
  float* ob = out + (baseRow + qpos) * (size_t)EMBED + head * HDIM + quad * 4;
  for (int dt = 0; dt < 4; ++dt) {
    float4 v;
    v.x = o_acc[dt][0] * inv;
    v.y = o_acc[dt][1] * inv;
    v.z = o_acc[dt][2] * inv;
    v.w = o_acc[dt][3] * inv;
    *(float4*)(ob + dt * 16) = v;
  }
#undef PREFETCH
}

extern "C" void kernel_launch(void* const* d_in, const int* in_sizes, int n_in,
                              void* d_out, int out_size, void* d_ws, size_t ws_size,
                              hipStream_t stream) {
  const float* h  = (const float*)d_in[0];
  const float* Wq = (const float*)d_in[1];
  const float* bq = (const float*)d_in[2];
  const float* Wk = (const float*)d_in[3];
  const float* bk = (const float*)d_in[4];
  const float* Wv = (const float*)d_in[5];
  const float* bv = (const float*)d_in[6];
  float* out = (float*)d_out;

  unsigned short* h_bf  = (unsigned short*)d_ws;                 // 16 MB
  unsigned short* wt_bf = h_bf + (size_t)M_TOT * K_DIM;          //  6 MB
  unsigned short* qk    = wt_bf + (size_t)N_QKV * K_DIM;         // 32 MB
  unsigned short* vtg   = qk + (size_t)M_TOT * N_QK;             // 16 MB  (total 70 MB)

  cvt_all<<<8192 + 3072, 256, 0, stream>>>(h, h_bf, Wq, Wk, Wv, wt_bf);
  qkv_gemm<<<dim3(8, 64), 512, 0, stream>>>(h_bf, wt_bf, bq, bk, bv, qk, vtg);
  attn<<<dim3(SEQ / 128, NHEAD, BSZ), 512, 0, stream>>>(qk, vtg, out);
}

// Round 14
// 195.235 us; speedup vs baseline: 1.4869x; 1.0508x over previous
//
#include <hip/hip_runtime.h>
#include <stdint.h>

#define SEQ    4096
#define EMBED  1024
#define NHEAD  16
#define HDIM   64
#define WIN    256
#define BSZ    2
#define M_TOT  (BSZ * SEQ)   // 8192
#define N_QKV  3072
#define N_QK   2048
#define K_DIM  1024
#define LOG2E  1.4426950408889634f

typedef __attribute__((ext_vector_type(8))) __bf16 bf16x8;
typedef __attribute__((ext_vector_type(4))) float  f32x4;

__device__ __forceinline__ unsigned short f2bf(float f) {
  union { float f; unsigned int u; } c; c.f = f;
  unsigned int u = c.u;
  unsigned int r = (u + 0x7FFFu + ((u >> 16) & 1u)) >> 16;
  return (unsigned short)r;
}

// packed f32x2 -> bf16x2 (RNE, same as f2bf) in ONE VALU instr
__device__ __forceinline__ unsigned int cvt_pk_bf16(float lo, float hi) {
  unsigned int r;
  asm("v_cvt_pk_bf16_f32 %0, %1, %2" : "=v"(r) : "v"(lo), "v"(hi));
  return r;
}

__device__ __forceinline__ void gl2lds16(const void* g, void* l) {
  __builtin_amdgcn_global_load_lds((const __attribute__((address_space(1))) void*)g,
                                   (__attribute__((address_space(3))) void*)l, 16, 0, 0);
}

// ---- merged cast kernel: blocks [0,8192) convert hidden_states (fp32->bf16),
// blocks [8192, 8192+3072) transpose+cast the three weight matrices.
__global__ __launch_bounds__(256) void cvt_all(const float* __restrict__ in,
                                               unsigned short* __restrict__ out,
                                               const float* __restrict__ Wq,
                                               const float* __restrict__ Wk,
                                               const float* __restrict__ Wv,
                                               unsigned short* __restrict__ Wt) {
  __shared__ float t[32][33];
  int tid = threadIdx.x;
  if (blockIdx.x < 8192) {
    int i = (blockIdx.x * 256 + tid) * 4;
    float4 v = *(const float4*)(in + i);
    ushort4 o;
    o.x = f2bf(v.x); o.y = f2bf(v.y); o.z = f2bf(v.z); o.w = f2bf(v.w);
    *(ushort4*)(out + i) = o;
  } else {
    int wb = blockIdx.x - 8192;                  // 0..3071
    int z  = wb >> 10;                           // 0..2
    int rem = wb & 1023;
    int kb = (rem & 31) * 32, nb = (rem >> 5) * 32;
    const float* W = (z == 0) ? Wq : (z == 1) ? Wk : Wv;
    int tx = tid & 31, ty = tid >> 5;            // (32,8)
    for (int it = 0; it < 4; ++it) {
      int k = kb + ty + it * 8;
      t[ty + it * 8][tx] = W[(size_t)k * 1024 + nb + tx];
    }
    __syncthreads();
    for (int it = 0; it < 4; ++it) {
      int n = nb + ty + it * 8;
      Wt[(size_t)(z * 1024 + n) * 1024 + kb + tx] = f2bf(t[tx][ty + it * 8]);
    }
  }
}

// ---- fused QKV GEMM: R14 = 128(M)x192(N) tile, BK=64, 8 waves (2Mx4N ->
// 64x48/wave), LDS 80 KB -> TWO blocks/CU (4 waves/SIMD). Rationale: R13
// proved staging-source latency non-binding (FETCH 57.5->41 MB, time flat);
// R2-R7 deep schedules all ran 1 block/CU and converged at 660-720 TF with
// every pipe <30% — the untested axis is schedule x occupancy. m114: separate
// blocks' waves co-issue MFMA while one block waits at a barrier; 1 block/CU
// forfeits that. Grid 64x16 = 1024 blocks = 4 rounds at 2/CU (even packing).
// Same verified R7 3-phase ledger, reparameterized (B = 3 regions of 64 rows,
// 1 sweep each):
//   p0: read af(8)+bf0(2); stage A(t+1)->alt [alt A last read t-1 p0];
//       barrier; MFMA j0(8); barrier
//   p1: read bf1(2); barrier; MFMA j1(8); barrier
//   p2: read bf2(2); barrier [ALL A+B reads of tile t done];
//       stage B0,B1,B2(t+2)->cur; MFMA j2(8); gate; barrier
// Gate: outstanding = B(t+1)3 + A(t+1)2 + B(t+2)3 = 8 -> vmcnt(3) retires
// A(t+1)+B(t+1) = exactly tile t+1. Drain vmcnt(0) at t>=14.
// L2-resident XCD swizzle kept (8 M-panels 2MB x 8 N-panels 3MB per XCD).
// T2 XOR-swizzle (zero bank conflicts since R1), T5 setprio.
__global__ __launch_bounds__(512, 4) void qkv_gemm(const unsigned short* __restrict__ A,   // h bf16 [8192][1024]
                                                   const unsigned short* __restrict__ Bt,  // Wt [3072][1024]
                                                   const float* __restrict__ bq,
                                                   const float* __restrict__ bk,
                                                   const float* __restrict__ bv,
                                                   unsigned short* __restrict__ C,         // qk [8192][2048]
                                                   unsigned short* __restrict__ Vt) {      // vtg [2048][4096]
  __shared__ unsigned short As[2][128 * 64];     // 2 x 16 KB
  __shared__ unsigned short Bs[2][192 * 64];     // 2 x 24 KB  (total 80 KB -> 2 blocks/CU)
  int tid  = threadIdx.x;
  int lane = tid & 63, wave = tid >> 6;          // 8 waves
  int ln   = lane & 15, quad = lane >> 4;
  // L2-resident XCD swizzle (bijective): 1024 blocks, 128 per XCD.
  int flat = blockIdx.y * 16 + blockIdx.x;       // 0..1023
  int xcd  = flat & 7, kk = flat >> 3;           // kk 0..127 per XCD
  int m0 = (xcd * 8 + (kk & 7)) * 128;           // 8 A-panels per XCD (2MB)
  int n0 = (kk >> 3) * 192;                      // 16 N-panels; ~8 co-resident (3MB)
  int wy = wave >> 2, wx = wave & 3;             // per-wave 64M x 48N
  f32x4 acc[4][3];
#pragma unroll
  for (int i = 0; i < 4; ++i)
#pragma unroll
    for (int j = 0; j < 3; ++j) acc[i][j] = (f32x4){0.f, 0.f, 0.f, 0.f};

  int c8 = tid & 7;

#define STG_A(buf, kt)                                                           \
  do {                                                                           \
    _Pragma("unroll")                                                            \
    for (int s = 0; s < 2; ++s) {                                                \
      int r = s * 64 + (tid >> 3); int cg = c8 ^ (r & 7);                        \
      gl2lds16(A + (size_t)(m0 + r) * K_DIM + (size_t)(kt) * 64 + cg * 8,        \
               &As[buf][r * 64 + c8 * 8]);                                       \
    }                                                                            \
  } while (0)
#define STG_B(buf, jreg, kt)                                                     \
  do {                                                                           \
    int r = tid >> 3; int gr = (jreg) * 64 + r;                                  \
    int cg = c8 ^ (gr & 7);                                                      \
    gl2lds16(Bt + (size_t)(n0 + gr) * K_DIM + (size_t)(kt) * 64 + cg * 8,        \
             &Bs[buf][gr * 64 + c8 * 8]);                                        \
  } while (0)

  // prologue: tile0 (A2+B3) + B(1)3 = 8 outstanding; vmcnt(3) retires tile 0
  STG_A(0, 0); STG_B(0, 0, 0); STG_B(0, 1, 0); STG_B(0, 2, 0);
  STG_B(1, 0, 1); STG_B(1, 1, 1); STG_B(1, 2, 1);
  asm volatile("s_waitcnt vmcnt(3)" ::: "memory");
  __builtin_amdgcn_s_barrier();

  int aBase = wy * 64, bBase = wx * 48;

#pragma unroll 1
  for (int t = 0; t < 16; ++t) {
    int cur = t & 1;
    const unsigned short* as = As[cur];
    const unsigned short* bs = Bs[cur];
    bf16x8 af[4][2], bf0[2], bf1[2], bf2[2];

    // ---- p0: read af(8) + bf0(2); stage A(t+1)->alt; MFMA j0
#pragma unroll
    for (int i2 = 0; i2 < 4; ++i2) {
      int row = aBase + i2 * 16 + ln;
#pragma unroll
      for (int ks = 0; ks < 2; ++ks) {
        int c = (ks * 4 + quad) ^ (row & 7);
        af[i2][ks] = *(const bf16x8*)&as[row * 64 + c * 8];
      }
    }
    {
      int row = bBase + ln;
#pragma unroll
      for (int ks = 0; ks < 2; ++ks) {
        int c = (ks * 4 + quad) ^ (row & 7);
        bf0[ks] = *(const bf16x8*)&bs[row * 64 + c * 8];
      }
    }
    if (t < 15) STG_A(cur ^ 1, t + 1);
    __builtin_amdgcn_s_barrier();
    __builtin_amdgcn_s_setprio(1);
#pragma unroll
    for (int ks = 0; ks < 2; ++ks)
#pragma unroll
      for (int i2 = 0; i2 < 4; ++i2)
        acc[i2][0] = __builtin_amdgcn_mfma_f32_16x16x32_bf16(af[i2][ks], bf0[ks], acc[i2][0], 0, 0, 0);
    __builtin_amdgcn_s_setprio(0);
    __builtin_amdgcn_s_barrier();

    // ---- p1: read bf1(2); MFMA j1
    {
      int row = bBase + 16 + ln;
#pragma unroll
      for (int ks = 0; ks < 2; ++ks) {
        int c = (ks * 4 + quad) ^ (row & 7);
        bf1[ks] = *(const bf16x8*)&bs[row * 64 + c * 8];
      }
    }
    __builtin_amdgcn_s_barrier();
    __builtin_amdgcn_s_setprio(1);
#pragma unroll
    for (int ks = 0; ks < 2; ++ks)
#pragma unroll
      for (int i2 = 0; i2 < 4; ++i2)
        acc[i2][1] = __builtin_amdgcn_mfma_f32_16x16x32_bf16(af[i2][ks], bf1[ks], acc[i2][1], 0, 0, 0);
    __builtin_amdgcn_s_setprio(0);
    __builtin_amdgcn_s_barrier();

    // ---- p2: read bf2(2); barrier (ALL A+B reads of tile t complete);
    //          stage B0,B1,B2(t+2)->cur; MFMA j2; gate
    {
      int row = bBase + 32 + ln;
#pragma unroll
      for (int ks = 0; ks < 2; ++ks) {
        int c = (ks * 4 + quad) ^ (row & 7);
        bf2[ks] = *(const bf16x8*)&bs[row * 64 + c * 8];
      }
    }
    __builtin_amdgcn_s_barrier();
    if (t < 14) { STG_B(cur, 0, t + 2); STG_B(cur, 1, t + 2); STG_B(cur, 2, t + 2); }
    __builtin_amdgcn_s_setprio(1);
#pragma unroll
    for (int ks = 0; ks < 2; ++ks)
#pragma unroll
      for (int i2 = 0; i2 < 4; ++i2)
        acc[i2][2] = __builtin_amdgcn_mfma_f32_16x16x32_bf16(af[i2][ks], bf2[ks], acc[i2][2], 0, 0, 0);
    __builtin_amdgcn_s_setprio(0);
    if (t < 14) asm volatile("s_waitcnt vmcnt(3)" ::: "memory");
    else        asm volatile("s_waitcnt vmcnt(0)" ::: "memory");
    __builtin_amdgcn_s_barrier();
  }
#undef STG_A
#undef STG_B

  // epilogue: 16-col j-tiles never straddle n=2048 (2048%16==0) -> branch per j
#pragma unroll
  for (int j = 0; j < 3; ++j) {
    int n = n0 + wx * 48 + j * 16 + ln;
    if (n < N_QK) {
      float bias, scl;
      if (n < 1024) { bias = bq[n];        scl = 0.125f * LOG2E; }  // fold 1/sqrt(64) and log2(e)
      else          { bias = bk[n - 1024]; scl = 1.f; }
#pragma unroll
      for (int i = 0; i < 4; ++i) {
        int mb = m0 + wy * 64 + i * 16 + quad * 4;
#pragma unroll
        for (int r = 0; r < 4; ++r) {
          float v = (acc[i][j][r] + bias) * scl;
          C[(size_t)(mb + r) * N_QK + n] = f2bf(v);
        }
      }
    } else {
      int hd = n - 2048;                     // head*64 + d
      float bias = bv[hd];
#pragma unroll
      for (int i = 0; i < 4; ++i) {
        int mb  = m0 + wy * 64 + i * 16 + quad * 4;
        int bb  = mb >> 12;                  // / SEQ
        int pos = mb & (SEQ - 1);
        ushort4 pk;
        pk.x = f2bf(acc[i][j][0] + bias);
        pk.y = f2bf(acc[i][j][1] + bias);
        pk.z = f2bf(acc[i][j][2] + bias);
        pk.w = f2bf(acc[i][j][3] + bias);
        *(ushort4*)&Vt[((size_t)bb * (NHEAD * HDIM) + hd) * SEQ + pos] = pk;
      }
    }
  }
}

// ------- banded flash attention -------
// R8 version EXACT (best total): 128 q / block (8 waves x 16 q, 512 thr),
// K/V staged via reg prefetch + LDS, 2 barriers/tile. R9 (dual-q), R10
// (dbuf 1-barrier), R11 (LDS-free) all regressed — R8 is the local optimum.
// Band mask: t<2 || t>=8. 18.4 KB LDS. FROZEN.
__global__ __launch_bounds__(512) void attn(const unsigned short* __restrict__ qk,
                                            const unsigned short* __restrict__ vtg,
                                            float* __restrict__ out) {
  __shared__ unsigned short Kl[64 * 72];
  __shared__ unsigned short Vl[64 * 72];
  int tid  = threadIdx.x;
  int lane = tid & 63, wave = tid >> 6;          // wave 0..7, 16 queries each
  int ln   = lane & 15, quad = lane >> 4;
  int bx = blockIdx.x;                           // 0..31
  int lx = ((bx & 7) << 2) | (bx >> 3);          // bijective XCD swizzle (32 = 8x4)
  int q0 = lx * 128, head = blockIdx.y, b = blockIdx.z;
  size_t baseRow = (size_t)b * SEQ;
  const unsigned short* kptr = qk + 1024;
  const unsigned short* vrow = vtg + ((size_t)(b * NHEAD + head) * HDIM) * SEQ;

  // per-thread staging coordinates (constant across tiles)
  int sy = tid >> 3, sc = tid & 7;               // row 0..63, 16B chunk 0..7
  const unsigned short* kbase = kptr + (baseRow + sy) * (size_t)N_QK + head * HDIM + sc * 8;
  const unsigned short* vbase = vrow + (size_t)sy * SEQ + sc * 8;

  // Q fragments from global (B-operand: n=q=ln, k = ks*32 + quad*8 + j)
  bf16x8 qf[2];
  {
    size_t ro = (baseRow + q0 + wave * 16 + ln) * (size_t)N_QK + head * HDIM + quad * 8;
    qf[0] = *(const bf16x8*)&qk[ro];
    qf[1] = *(const bf16x8*)&qk[ro + 32];
  }

  float l_st = 0.f;
  f32x4 o_acc[4];                                // O^T: row d = dt*16+quad*4+r, col q = ln
  for (int dt = 0; dt < 4; ++dt) o_acc[dt] = (f32x4){0.f, 0.f, 0.f, 0.f};

  int lo = (q0 >= 256) ? 0 : (256 - q0) / 64;
  int hi = (SEQ + 256 - q0) / 64; if (hi > 10) hi = 10;

  uint4 pk, pv;
#define PREFETCH(KT)                                                        \
  {                                                                         \
    pk = *(const uint4*)&kbase[(size_t)(KT) * N_QK];                        \
    pv = *(const uint4*)&vbase[(KT)];                                       \
  }

  PREFETCH(q0 - 256 + lo * 64);

  int srcA = ((lane & 16) << 1) | ln;            // (quad&1)*32 + ln
  int srcB = srcA + 16;
  bool hiQ = (lane & 32) != 0;                   // quad >= 2

  for (int t = lo; t < hi; ++t) {
    int kt = q0 - 256 + t * 64;
    __syncthreads();                                   // A: prev-tile LDS reads drained
    *(uint4*)&Kl[sy * 72 + sc * 8] = pk;
    *(uint4*)&Vl[sy * 72 + sc * 8] = pv;
    __syncthreads();                                   // B: staging visible

    if (t + 1 < hi) { PREFETCH(kt + 64); }             // hide HBM latency behind compute

    // S^T = K Q^T : row k = kt + nt*16 + quad*4 + r, col q = ln  (kf loaded JIT)
    f32x4 s[4];
    __builtin_amdgcn_s_setprio(1);
    for (int nt = 0; nt < 4; ++nt) {
      bf16x8 kf0 = *(const bf16x8*)&Kl[(nt * 16 + ln) * 72 + quad * 8];
      bf16x8 kf1 = *(const bf16x8*)&Kl[(nt * 16 + ln) * 72 + 32 + quad * 8];
      f32x4 z = (f32x4){0.f, 0.f, 0.f, 0.f};
      z = __builtin_amdgcn_mfma_f32_16x16x32_bf16(kf0, qf[0], z, 0, 0, 0);
      z = __builtin_amdgcn_mfma_f32_16x16x32_bf16(kf1, qf[1], z, 0, 0, 0);
      s[nt] = z;
    }
    __builtin_amdgcn_s_setprio(0);

    if (t < 2 || t >= 8) {                             // only edge tiles need band mask
      int qq = q0 + wave * 16 + ln;
      for (int nt = 0; nt < 4; ++nt) {
        int kb = kt + nt * 16 + quad * 4 - qq;
        for (int r = 0; r < 4; ++r) {
          int dd = kb + r;
          if (dd < -WIN || dd > WIN) s[nt][r] = -INFINITY;
        }
      }
    }

    // fixed-max softmax (scores in log2 units; masked -> exp2(-inf) = 0)
    float rs = 0.f;
    for (int nt = 0; nt < 4; ++nt)
      for (int r = 0; r < 4; ++r) {
        float p = exp2f(s[nt][r]);
        s[nt][r] = p;
        rs += p;
      }
    l_st += rs;

    // pack P to bf16 pairs (per nt: elements 0,1 and 2,3) — one v_cvt_pk each
    unsigned int p01[4], p23[4];
    for (int nt = 0; nt < 4; ++nt) {
      p01[nt] = cvt_pk_bf16(s[nt][0], s[nt][1]);
      p23[nt] = cvt_pk_bf16(s[nt][2], s[nt][3]);
    }

    // O^T += V^T P : A = V^T [d][k] from Vl, B = P[k][q] built via shuffles
    for (int ks = 0; ks < 2; ++ks) {
      int ntA = 2 * ks, ntB = 2 * ks + 1;
      unsigned int a0 = (unsigned int)__shfl((int)p01[ntA], srcA);
      unsigned int a1 = (unsigned int)__shfl((int)p23[ntA], srcA);
      unsigned int a2 = (unsigned int)__shfl((int)p01[ntA], srcB);
      unsigned int a3 = (unsigned int)__shfl((int)p23[ntA], srcB);
      unsigned int b0 = (unsigned int)__shfl((int)p01[ntB], srcA);
      unsigned int b1 = (unsigned int)__shfl((int)p23[ntB], srcA);
      unsigned int b2 = (unsigned int)__shfl((int)p01[ntB], srcB);
      unsigned int b3 = (unsigned int)__shfl((int)p23[ntB], srcB);
      union { uint4 u; bf16x8 v; } pf;
      pf.u.x = hiQ ? b0 : a0;
      pf.u.y = hiQ ? b1 : a1;
      pf.u.z = hiQ ? b2 : a2;
      pf.u.w = hiQ ? b3 : a3;
      __builtin_amdgcn_s_setprio(1);
      for (int dt = 0; dt < 4; ++dt) {
        bf16x8 vf = *(const bf16x8*)&Vl[(dt * 16 + ln) * 72 + ks * 32 + quad * 8];
        o_acc[dt] = __builtin_amdgcn_mfma_f32_16x16x32_bf16(vf, pf.v, o_acc[dt], 0, 0, 0);
      }
      __builtin_amdgcn_s_setprio(0);
    }
  }

  // l reduction across the 4 quads of column q=ln; per-lane inverse, float4 stores
  float l = l_st;
  l += __shfl_xor(l, 16);
  l += __shfl_xor(l, 32);
  float inv = 1.0f / l;
  int qpos = q0 + wave * 16 + ln;
  float* ob = out + (baseRow + qpos) * (size_t)EMBED + head * HDIM + quad * 4;
  for (int dt = 0; dt < 4; ++dt) {
    float4 v;
    v.x = o_acc[dt][0] * inv;
    v.y = o_acc[dt][1] * inv;
    v.z = o_acc[dt][2] * inv;
    v.w = o_acc[dt][3] * inv;
    *(float4*)(ob + dt * 16) = v;
  }
#undef PREFETCH
}

extern "C" void kernel_launch(void* const* d_in, const int* in_sizes, int n_in,
                              void* d_out, int out_size, void* d_ws, size_t ws_size,
                              hipStream_t stream) {
  const float* h  = (const float*)d_in[0];
  const float* Wq = (const float*)d_in[1];
  const float* bq = (const float*)d_in[2];
  const float* Wk = (const float*)d_in[3];
  const float* bk = (const float*)d_in[4];
  const float* Wv = (const float*)d_in[5];
  const float* bv = (const float*)d_in[6];
  float* out = (float*)d_out;

  unsigned short* h_bf  = (unsigned short*)d_ws;                 // 16 MB
  unsigned short* wt_bf = h_bf + (size_t)M_TOT * K_DIM;          //  6 MB
  unsigned short* qk    = wt_bf + (size_t)N_QKV * K_DIM;         // 32 MB
  unsigned short* vtg   = qk + (size_t)M_TOT * N_QK;             // 16 MB  (total 70 MB)

  cvt_all<<<8192 + 3072, 256, 0, stream>>>(h, h_bf, Wq, Wk, Wv, wt_bf);
  qkv_gemm<<<dim3(16, 64), 512, 0, stream>>>(h_bf, wt_bf, bq, bk, bv, qk, vtg);
  attn<<<dim3(SEQ / 128, NHEAD, BSZ), 512, 0, stream>>>(qk, vtg, out);
}